// Round 3
// baseline (468.567 us; speedup 1.0000x reference)
//
#include <hip/hip_runtime.h>
#include <cstdint>
#include <cstddef>

typedef float   f32x4 __attribute__((ext_vector_type(4)));
typedef _Float16 f16x8 __attribute__((ext_vector_type(8)));
typedef _Float16 f16x4 __attribute__((ext_vector_type(4)));

#define TOK  4096
#define HID  1024
#define IDIM 4096
#define LDP  40   // padded stride (halfs) for manually-staged A tiles

#define GAS __attribute__((address_space(1)))
#define LAS __attribute__((address_space(3)))

// async 16B global -> LDS (wave-uniform base + lane*16 layout required)
__device__ __forceinline__ void gld16(const void* g, void* l) {
    __builtin_amdgcn_global_load_lds((const GAS unsigned int*)g,
                                     (LAS unsigned int*)l, 16, 0, 0);
}

// ---------------------------------------------------------------------------
// Dense: h = hs(fp32) @ dense_w^T + dense_b.  Tile 128x32, grid (32,32) = 1024
// blocks -> 4 blocks/CU. A: fp32 load + cvt + ds_write (padded). B: async LDS.
// 4 waves: 2M x 2N, wave 64x16 (4x1 MFMA 16x16x32).
// ---------------------------------------------------------------------------
__global__ __launch_bounds__(256, 4) void gemm_dense(
    const float* __restrict__ Af, const _Float16* __restrict__ B,
    const float* __restrict__ bias, float* __restrict__ outF)
{
    __shared__ _Float16 lA[128 * LDP];
    __shared__ _Float16 lB[32 * 32];
    const int tid = threadIdx.x, lane = tid & 63, wave = tid >> 6;
    const int m0 = blockIdx.x * 128;
    const int n0 = blockIdx.y * 32;
    const int wM = (wave & 1) * 64;
    const int wN = (wave >> 1) * 16;
    const int arow = tid >> 2, akc = tid & 3;
    const float* ap0 = Af + (size_t)(m0 + arow) * IDIM + akc * 8;
    const float* ap1 = Af + (size_t)(m0 + 64 + arow) * IDIM + akc * 8;
    _Float16* ld0 = lA + arow * LDP + akc * 8;
    _Float16* ld1 = lA + (64 + arow) * LDP + akc * 8;
    const _Float16* bp = B + (size_t)(n0 + arow) * IDIM + akc * 8;
    _Float16* lbd = lB + tid * 8;
    const int fr = lane & 15, kc8 = (lane >> 4) * 8;
    f32x4 acc[4] = {};

    for (int k0 = 0; k0 < IDIM; k0 += 32) {
        if (tid < 128) gld16(bp + k0, lbd);
        f32x4 a0 = *(const f32x4*)(ap0 + k0);
        f32x4 a1 = *(const f32x4*)(ap0 + k0 + 4);
        f32x4 a2 = *(const f32x4*)(ap1 + k0);
        f32x4 a3 = *(const f32x4*)(ap1 + k0 + 4);
        f16x8 o0, o1;
#pragma unroll
        for (int j = 0; j < 4; ++j) {
            o0[j] = (_Float16)a0[j]; o0[4 + j] = (_Float16)a1[j];
            o1[j] = (_Float16)a2[j]; o1[4 + j] = (_Float16)a3[j];
        }
        *(f16x8*)ld0 = o0;
        *(f16x8*)ld1 = o1;
        __syncthreads();
        f16x8 bfr = *(const f16x8*)(lB + (wN + fr) * 32 + kc8);
#pragma unroll
        for (int mi = 0; mi < 4; ++mi) {
            f16x8 afr = *(const f16x8*)(lA + (wM + mi * 16 + fr) * LDP + kc8);
            acc[mi] = __builtin_amdgcn_mfma_f32_16x16x32_f16(afr, bfr, acc[mi], 0, 0, 0);
        }
        __syncthreads();
    }

    const int cn = lane & 15, rq = (lane >> 4) * 4;
    const int n = n0 + wN + cn;
    const float bb = bias[n];
#pragma unroll
    for (int mi = 0; mi < 4; ++mi)
#pragma unroll
        for (int r = 0; r < 4; ++r) {
            const int m = m0 + wM + mi * 16 + rq + r;
            outF[(size_t)m * HID + n] = acc[mi][r] + bb;
        }
}

// ---------------------------------------------------------------------------
// f16 NT GEMM, 128x64 tile, 256 thr, 4 waves 2x2 (wave 64x32). Full async LDS.
// MODE 0 (dual, z): z0: down=relu(acc+cb)  z1: g=acc+cb2   (both f16, ldC=512)
// MODE 1 (mixed): f16 = acc + addv + sum_t probs*upb        (ldC=1024)
// MODE 2 (fuse):  f32 = acc + addv                          (ldC=1024)
// ---------------------------------------------------------------------------
template <int MODE>
__global__ __launch_bounds__(256, 4) void gemmA(
    const _Float16* __restrict__ A, const _Float16* __restrict__ B, int K, int ldC,
    _Float16* __restrict__ outH, float* __restrict__ outF,
    const float* __restrict__ cbias, const float* __restrict__ addv,
    const float* __restrict__ probs, const float* __restrict__ upb,
    const _Float16* __restrict__ A2, const _Float16* __restrict__ B2,
    _Float16* __restrict__ outH2, const float* __restrict__ cbias2)
{
    __shared__ _Float16 lA[128 * 32];
    __shared__ _Float16 lB[64 * 32];
    const int tid = threadIdx.x, lane = tid & 63, wave = tid >> 6;
    int zz = 0;
    if constexpr (MODE == 0) {
        zz = blockIdx.z;
        if (zz) { A = A2; B = B2; }
    }
    const int m0 = blockIdx.x * 128;
    const int n0 = blockIdx.y * 64;
    const int wM = (wave & 1) * 64;
    const int wN = (wave >> 1) * 32;
    const int arow = tid >> 2, akc = tid & 3;
    const _Float16* ap0 = A + (size_t)(m0 + arow) * K + akc * 8;
    const _Float16* ap1 = A + (size_t)(m0 + 64 + arow) * K + akc * 8;
    const _Float16* bp  = B + (size_t)(n0 + arow) * K + akc * 8;
    _Float16* l0 = lA + tid * 8;
    _Float16* l1 = lA + (256 + tid) * 8;
    _Float16* lb = lB + tid * 8;
    const int fr = lane & 15, kc8 = (lane >> 4) * 8;
    f32x4 acc[4][2] = {};

    for (int k0 = 0; k0 < K; k0 += 32) {
        gld16(ap0 + k0, l0);
        gld16(ap1 + k0, l1);
        gld16(bp + k0, lb);
        __syncthreads();
        f16x8 afr[4], bfr[2];
#pragma unroll
        for (int mi = 0; mi < 4; ++mi)
            afr[mi] = *(const f16x8*)(lA + (wM + mi * 16 + fr) * 32 + kc8);
#pragma unroll
        for (int ni = 0; ni < 2; ++ni)
            bfr[ni] = *(const f16x8*)(lB + (wN + ni * 16 + fr) * 32 + kc8);
#pragma unroll
        for (int mi = 0; mi < 4; ++mi)
#pragma unroll
            for (int ni = 0; ni < 2; ++ni)
                acc[mi][ni] = __builtin_amdgcn_mfma_f32_16x16x32_f16(
                    afr[mi], bfr[ni], acc[mi][ni], 0, 0, 0);
        __syncthreads();
    }

    const int cn = lane & 15, rq = (lane >> 4) * 4;
#pragma unroll
    for (int mi = 0; mi < 4; ++mi)
#pragma unroll
        for (int r = 0; r < 4; ++r) {
            const int m = m0 + wM + mi * 16 + rq + r;
#pragma unroll
            for (int ni = 0; ni < 2; ++ni) {
                const int n = n0 + wN + ni * 16 + cn;
                const size_t idx = (size_t)m * ldC + n;
                const float v = acc[mi][ni][r];
                if constexpr (MODE == 0) {
                    if (!zz) {
                        const float y = v + cbias[n];
                        outH[idx] = (_Float16)(y > 0.f ? y : 0.f);
                    } else {
                        outH2[idx] = (_Float16)(v + cbias2[n]);
                    }
                } else if constexpr (MODE == 1) {
                    float s = v + addv[idx];
#pragma unroll
                    for (int t = 0; t < 8; ++t)
                        s += probs[(size_t)m * 8 + t] * upb[t * 1024 + n];
                    outH[idx] = (_Float16)s;
                } else {
                    outF[idx] = v + addv[idx];
                }
            }
        }
}

// ---------------------------------------------------------------------------
// f16 NT weight GEMM, 64x64 tile (for P and WgT), f16 out, no bias.
// ---------------------------------------------------------------------------
__global__ __launch_bounds__(256, 4) void gemmW(
    const _Float16* __restrict__ A, const _Float16* __restrict__ B, int K, int ldC,
    _Float16* __restrict__ outH)
{
    __shared__ _Float16 lA[64 * 32];
    __shared__ _Float16 lB[64 * 32];
    const int tid = threadIdx.x, lane = tid & 63, wave = tid >> 6;
    const int m0 = blockIdx.x * 64;
    const int n0 = blockIdx.y * 64;
    const int wM = (wave & 1) * 32;
    const int wN = (wave >> 1) * 32;
    const int arow = tid >> 2, akc = tid & 3;
    const _Float16* ap = A + (size_t)(m0 + arow) * K + akc * 8;
    const _Float16* bp = B + (size_t)(n0 + arow) * K + akc * 8;
    _Float16* la = lA + tid * 8;
    _Float16* lb = lB + tid * 8;
    const int fr = lane & 15, kc8 = (lane >> 4) * 8;
    f32x4 acc[2][2] = {};

    for (int k0 = 0; k0 < K; k0 += 32) {
        gld16(ap + k0, la);
        gld16(bp + k0, lb);
        __syncthreads();
        f16x8 afr[2], bfr[2];
#pragma unroll
        for (int mi = 0; mi < 2; ++mi)
            afr[mi] = *(const f16x8*)(lA + (wM + mi * 16 + fr) * 32 + kc8);
#pragma unroll
        for (int ni = 0; ni < 2; ++ni)
            bfr[ni] = *(const f16x8*)(lB + (wN + ni * 16 + fr) * 32 + kc8);
#pragma unroll
        for (int mi = 0; mi < 2; ++mi)
#pragma unroll
            for (int ni = 0; ni < 2; ++ni)
                acc[mi][ni] = __builtin_amdgcn_mfma_f32_16x16x32_f16(
                    afr[mi], bfr[ni], acc[mi][ni], 0, 0, 0);
        __syncthreads();
    }

    const int cn = lane & 15, rq = (lane >> 4) * 4;
#pragma unroll
    for (int mi = 0; mi < 2; ++mi)
#pragma unroll
        for (int r = 0; r < 4; ++r) {
            const int m = m0 + wM + mi * 16 + rq + r;
#pragma unroll
            for (int ni = 0; ni < 2; ++ni) {
                const int n = n0 + wN + ni * 16 + cn;
                outH[(size_t)m * ldC + n] = (_Float16)acc[mi][ni][r];
            }
        }
}

// ---------------------------------------------------------------------------
// LN over prenorm = h + it; emits ai (f16) and pn (f16)
// ---------------------------------------------------------------------------
__global__ __launch_bounds__(256) void ln_adapter(
    const float* __restrict__ hbuf, const float* __restrict__ it,
    const float* __restrict__ gam, const float* __restrict__ bet,
    _Float16* __restrict__ ai, _Float16* __restrict__ pn)
{
    const int n = blockIdx.x, tid = threadIdx.x;
    const int lane = tid & 63, wave = tid >> 6;
    const size_t base = (size_t)n * 1024 + tid * 4;
    f32x4 hv = *(const f32x4*)(hbuf + base);
    f32x4 iv = *(const f32x4*)(it + base);
    f32x4 x = hv + iv;
    float s = x[0] + x[1] + x[2] + x[3];
    float q = x[0] * x[0] + x[1] * x[1] + x[2] * x[2] + x[3] * x[3];
#pragma unroll
    for (int off = 1; off < 64; off <<= 1) {
        s += __shfl_xor(s, off);
        q += __shfl_xor(q, off);
    }
    __shared__ float rs[4], rq[4];
    if (lane == 0) { rs[wave] = s; rq[wave] = q; }
    __syncthreads();
    s = rs[0] + rs[1] + rs[2] + rs[3];
    q = rq[0] + rq[1] + rq[2] + rq[3];
    const float mu = s * (1.f / 1024.f);
    const float var = q * (1.f / 1024.f) - mu * mu;
    const float rstd = rsqrtf(var + 1e-12f);
    f32x4 gv = *(const f32x4*)(gam + tid * 4);
    f32x4 bv = *(const f32x4*)(bet + tid * 4);
    f16x4 av, pv;
#pragma unroll
    for (int j = 0; j < 4; ++j) {
        const float y = (x[j] - mu) * rstd * gv[j] + bv[j];
        av[j] = (_Float16)y;
        pv[j] = (_Float16)x[j];
    }
    *(f16x4*)(ai + base) = av;
    *(f16x4*)(pn + base) = pv;
}

__global__ __launch_bounds__(256) void ln_out(
    const float* __restrict__ fuse, const float* __restrict__ gam,
    const float* __restrict__ bet, float* __restrict__ outp)
{
    const int n = blockIdx.x, tid = threadIdx.x;
    const int lane = tid & 63, wave = tid >> 6;
    const size_t base = (size_t)n * 1024 + tid * 4;
    f32x4 x = *(const f32x4*)(fuse + base);
    float s = x[0] + x[1] + x[2] + x[3];
    float q = x[0] * x[0] + x[1] * x[1] + x[2] * x[2] + x[3] * x[3];
#pragma unroll
    for (int off = 1; off < 64; off <<= 1) {
        s += __shfl_xor(s, off);
        q += __shfl_xor(q, off);
    }
    __shared__ float rs[4], rq[4];
    if (lane == 0) { rs[wave] = s; rq[wave] = q; }
    __syncthreads();
    s = rs[0] + rs[1] + rs[2] + rs[3];
    q = rq[0] + rq[1] + rq[2] + rq[3];
    const float mu = s * (1.f / 1024.f);
    const float var = q * (1.f / 1024.f) - mu * mu;
    const float rstd = rsqrtf(var + 1e-12f);
    f32x4 gv = *(const f32x4*)(gam + tid * 4);
    f32x4 bv = *(const f32x4*)(bet + tid * 4);
    f32x4 y;
#pragma unroll
    for (int j = 0; j < 4; ++j) y[j] = (x[j] - mu) * rstd * gv[j] + bv[j];
    *(f32x4*)(outp + base) = y;
}

// ---------------------------------------------------------------------------
// scores v2: per token n, from pn only.
// sc[t] = down.g|task t + pn.U9[:,t] + cts[t] + (pn.U9[:,8] + cts[8])
// ---------------------------------------------------------------------------
__global__ __launch_bounds__(256) void scores2(
    const _Float16* __restrict__ pn, const float* __restrict__ U9,
    const float* __restrict__ cts,
    const _Float16* __restrict__ down, const _Float16* __restrict__ g,
    float* __restrict__ probs_out, _Float16* __restrict__ wdown)
{
    const int n = blockIdx.x, tid = threadIdx.x;
    const int lane = tid & 63, wave = tid >> 6;
    const _Float16* prow = pn + (size_t)n * 1024;
    float a9[9] = {};
#pragma unroll
    for (int j = 0; j < 4; ++j) {
        const int h = tid + j * 256;
        const float ph = (float)prow[h];
        const float* u = U9 + h * 12;
        f32x4 u0 = *(const f32x4*)u;
        f32x4 u1 = *(const f32x4*)(u + 4);
#pragma unroll
        for (int k = 0; k < 4; ++k) { a9[k] += ph * u0[k]; a9[4 + k] += ph * u1[k]; }
        a9[8] += ph * u[8];
    }
#pragma unroll
    for (int off = 1; off < 64; off <<= 1)
#pragma unroll
        for (int k = 0; k < 9; ++k) a9[k] += __shfl_xor(a9[k], off);
    __shared__ float red[4][9];
    __shared__ float sd[8];
    __shared__ float pl[8];
    if (lane == 0)
#pragma unroll
        for (int k = 0; k < 9; ++k) red[wave][k] = a9[k];
    // per-task down.g
    const int c0i = tid * 2;
    const size_t dbase = (size_t)n * 512;
    const float d0 = (float)down[dbase + c0i];
    const float d1 = (float)down[dbase + c0i + 1];
    float pz = d0 * (float)g[dbase + c0i] + d1 * (float)g[dbase + c0i + 1];
#pragma unroll
    for (int off = 1; off < 32; off <<= 1) pz += __shfl_xor(pz, off);
    if ((lane & 31) == 0) sd[wave * 2 + (lane >> 5)] = pz;
    __syncthreads();
    if (tid == 0) {
        float qb = cts[8];
#pragma unroll
        for (int w = 0; w < 4; ++w) qb += red[w][8];
        float sc[8];
        float mx = -1e30f;
#pragma unroll
        for (int t = 0; t < 8; ++t) {
            float v = sd[t] + cts[t] + qb;
#pragma unroll
            for (int w = 0; w < 4; ++w) v += red[w][t];
            sc[t] = v;
            mx = fmaxf(mx, v);
        }
        float sum = 0.f;
#pragma unroll
        for (int t = 0; t < 8; ++t) { sc[t] = expf(sc[t] - mx); sum += sc[t]; }
        const float inv = 1.f / sum;
#pragma unroll
        for (int t = 0; t < 8; ++t) pl[t] = sc[t] * inv;
    }
    __syncthreads();
    const float pr = pl[c0i >> 6];
    wdown[dbase + c0i]     = (_Float16)(pr * d0);
    wdown[dbase + c0i + 1] = (_Float16)(pr * d1);
    if (tid < 8) probs_out[(size_t)n * 8 + tid] = pl[tid];
}

// ---------------------------------------------------------------------------
// prep: f16 conversions + up_w reshapes
// ---------------------------------------------------------------------------
__device__ inline void cvt_seg(const float* __restrict__ s, _Float16* __restrict__ d,
                               int n4, int gid, int gsz)
{
    for (int i = gid; i < n4; i += gsz) {
        f32x4 v = ((const f32x4*)s)[i];
        f16x4 o;
        o[0] = (_Float16)v[0]; o[1] = (_Float16)v[1];
        o[2] = (_Float16)v[2]; o[3] = (_Float16)v[3];
        ((f16x4*)d)[i] = o;
    }
}

__global__ __launch_bounds__(256) void prep_all(
    const float* dw, _Float16* o_dw,
    const float* vw, _Float16* o_vw,
    const float* kw, _Float16* o_kw,
    const float* dnw, _Float16* o_dnw,
    const float* upw, _Float16* o_upg, _Float16* o_upmix)
{
    const int gid = blockIdx.x * 256 + threadIdx.x;
    const int gsz = gridDim.x * 256;
    cvt_seg(dw,  o_dw,  HID * IDIM / 4, gid, gsz);
    cvt_seg(vw,  o_vw,  HID * HID / 4,  gid, gsz);
    cvt_seg(kw,  o_kw,  HID * HID / 4,  gid, gsz);
    cvt_seg(dnw, o_dnw, 512 * HID / 4,  gid, gsz);
    for (int i = gid; i < 8 * HID * 64; i += gsz) {
        const int d = i & 63;
        const int h = (i >> 6) & 1023;
        const int t = i >> 16;
        const _Float16 v = (_Float16)upw[i];
        o_upg[(size_t)(t * 64 + d) * 1024 + h] = v;
        o_upmix[(size_t)h * 512 + t * 64 + d]  = v;
    }
}

// query_w [q,h] -> w_qT [h,q] (f16)
__global__ __launch_bounds__(256) void transpose_q(
    const float* __restrict__ in, _Float16* __restrict__ outp)
{
    __shared__ float t[32][33];
    const int bx = blockIdx.x * 32;
    const int by = blockIdx.y * 32;
    const int tx = threadIdx.x & 31, ty = threadIdx.x >> 5;
#pragma unroll
    for (int j = 0; j < 32; j += 8)
        t[ty + j][tx] = in[(size_t)(by + ty + j) * 1024 + bx + tx];
    __syncthreads();
#pragma unroll
    for (int j = 0; j < 32; j += 8)
        outp[(size_t)(bx + ty + j) * 1024 + by + tx] = (_Float16)t[tx][ty + j];
}

// ---------------------------------------------------------------------------
// sv1: V[q,t] = key_w[q,:].up_b[t,:]; U9[:,8]=qkb (key_b @ query_w); cts[8]=c0
// grid 37 blocks x 256
// ---------------------------------------------------------------------------
__global__ __launch_bounds__(256) void sv1(
    const float* __restrict__ key_w, const float* __restrict__ up_b,
    const float* __restrict__ query_w, const float* __restrict__ query_b,
    const float* __restrict__ key_b,
    float* __restrict__ V, float* __restrict__ U9, float* __restrict__ cts)
{
    const int b = blockIdx.x, tid = threadIdx.x;
    if (b < 32) {
        const int q = b * 32 + (tid >> 3);
        const int t = tid & 7;
        const float* kr = key_w + (size_t)q * 1024;
        const float* ur = up_b + (size_t)t * 1024;
        float acc = 0.f;
        for (int h = 0; h < 1024; ++h) acc += kr[h] * ur[h];
        V[q * 8 + t] = acc;
    } else if (b < 36) {
        const int h1 = (b - 32) * 256 + tid;
        float acc = 0.f;
        for (int q = 0; q < 1024; ++q) acc += key_b[q] * query_w[(size_t)q * 1024 + h1];
        U9[h1 * 12 + 8] = acc;
    } else {
        float acc = 0.f;
        for (int q = tid; q < 1024; q += 256) acc += query_b[q] * key_b[q];
#pragma unroll
        for (int off = 1; off < 64; off <<= 1) acc += __shfl_xor(acc, off);
        __shared__ float r[4];
        if ((tid & 63) == 0) r[tid >> 6] = acc;
        __syncthreads();
        if (tid == 0) cts[8] = r[0] + r[1] + r[2] + r[3];
    }
}

// ---------------------------------------------------------------------------
// sv2: U9[h1,t] = WqT[h1,:].V[:,t]; bg[td] = P[td,:].query_b; cts[t]=query_b.V[:,t]
// grid 35 blocks x 256
// ---------------------------------------------------------------------------
__global__ __launch_bounds__(256) void sv2(
    const _Float16* __restrict__ w_qT, const _Float16* __restrict__ P,
    const float* __restrict__ V, const float* __restrict__ query_b,
    float* __restrict__ U9, float* __restrict__ bg, float* __restrict__ cts)
{
    const int b = blockIdx.x, tid = threadIdx.x;
    if (b < 32) {
        const int h1 = b * 32 + (tid >> 3);
        const int t = tid & 7;
        const _Float16* wr = w_qT + (size_t)h1 * 1024;
        float acc = 0.f;
        for (int q = 0; q < 1024; ++q) acc += (float)wr[q] * V[q * 8 + t];
        U9[h1 * 12 + t] = acc;
    } else if (b < 34) {
        const int td = (b - 32) * 256 + tid;
        const _Float16* pr = P + (size_t)td * 1024;
        float acc = 0.f;
        for (int q = 0; q < 1024; ++q) acc += (float)pr[q] * query_b[q];
        bg[td] = acc;
    } else {
        const int t = tid >> 5;
        float acc = 0.f;
        for (int q = tid & 31; q < 1024; q += 32) acc += V[q * 8 + t] * query_b[q];
#pragma unroll
        for (int off = 1; off < 32; off <<= 1) acc += __shfl_xor(acc, off);
        if ((tid & 31) == 0) cts[t] = acc;
    }
}

// ---------------------------------------------------------------------------
extern "C" void kernel_launch(void* const* d_in, const int* in_sizes, int n_in,
                              void* d_out, int out_size, void* d_ws, size_t ws_size,
                              hipStream_t stream)
{
    const float* hs      = (const float*)d_in[0];
    const float* it      = (const float*)d_in[1];
    const float* dense_w = (const float*)d_in[2];
    const float* dense_b = (const float*)d_in[3];
    const float* ln_g    = (const float*)d_in[4];
    const float* ln_b    = (const float*)d_in[5];
    const float* down_w  = (const float*)d_in[6];
    const float* down_b  = (const float*)d_in[7];
    const float* up_w    = (const float*)d_in[8];
    const float* up_b    = (const float*)d_in[9];
    const float* key_w   = (const float*)d_in[10];
    const float* key_b   = (const float*)d_in[11];
    const float* query_w = (const float*)d_in[12];
    const float* query_b = (const float*)d_in[13];
    const float* value_w = (const float*)d_in[14];
    float* outp = (float*)d_out;
    (void)in_sizes; (void)n_in; (void)out_size; (void)ws_size;

    char* base = (char*)d_ws;
    _Float16* w_dense = (_Float16*)(base);             //  8 MiB
    _Float16* w_value = (_Float16*)(base +  8388608);  //  2
    _Float16* w_down  = (_Float16*)(base + 10485760);  //  1
    _Float16* w_upg   = (_Float16*)(base + 11534336);  //  1
    _Float16* w_upmix = (_Float16*)(base + 12582912);  //  1
    _Float16* w_key16 = (_Float16*)(base + 13631488);  //  2
    _Float16* w_qT    = (_Float16*)(base + 15728640);  //  2
    _Float16* P       = (_Float16*)(base + 17825792);  //  1
    _Float16* WgT     = (_Float16*)(base + 18874368);  //  1
    float*    U9      = (float*)(base + 19922944);     //  48 KiB ([1024][12])
    float*    V       = (float*)(base + 19972096);     //  32 KiB
    float*    bg      = (float*)(base + 20004864);     //  2 KiB
    float*    cts     = (float*)(base + 20006912);     //  64 B
    // region X (20.125 MiB, all written after ln_adapter)
    char* X = base + 20971520;
    _Float16* wdown = (_Float16*)(X);                  //  4 MiB
    float*    probs = (float*)(X + 4194304);           //  128 KiB
    _Float16* down  = (_Float16*)(X + 4325376);        //  4 MiB  } overlaid by
    _Float16* g     = (_Float16*)(X + 8519680);        //  4 MiB  } fuse later
    float*    fuse  = (float*)(X + 4325376);           // 16 MiB (down/g dead)
    _Float16* pn    = (_Float16*)(base + 42074112);    //  8 MiB
    _Float16* ai    = (_Float16*)(base + 50462720);    //  8 MiB (reused: mixed)
    float*    h_f32 = (float*)(base + 58851328);       // 16 MiB  -> end 72.1 MiB
    _Float16* mixed = ai;

    // 1. weight conversions / reshapes
    prep_all<<<1024, 256, 0, stream>>>(dense_w, w_dense, value_w, w_value,
                                       key_w, w_key16, down_w, w_down,
                                       up_w, w_upg, w_upmix);
    // 2. w_qT = query_w^T
    transpose_q<<<dim3(32, 32), 256, 0, stream>>>(query_w, w_qT);
    // 3. V, qkb(U9 col8), c0(cts[8])
    sv1<<<37, 256, 0, stream>>>(key_w, up_b, query_w, query_b, key_b, V, U9, cts);
    // 4. h = hs @ dense_w^T + dense_b
    gemm_dense<<<dim3(32, 32), 256, 0, stream>>>(hs, w_dense, dense_b, h_f32);
    // 5. ai = LN(h + it), pn = f16(h + it)
    ln_adapter<<<TOK, 256, 0, stream>>>(h_f32, it, ln_g, ln_b, ai, pn);
    // 6. P = w_upg @ w_key16^T        [512 x 1024]
    gemmW<<<dim3(8, 16), 256, 0, stream>>>(w_upg, w_key16, HID, HID, P);
    // 7. WgT = P @ w_qT^T             [512 x 1024]
    gemmW<<<dim3(8, 16), 256, 0, stream>>>(P, w_qT, HID, HID, WgT);
    // 8. U9 cols 0-7, bg, cts 0-7
    sv2<<<35, 256, 0, stream>>>(w_qT, P, V, query_b, U9, bg, cts);
    // 9. dual: down = relu(ai @ w_down^T + down_b); g = pn @ WgT^T + bg
    gemmA<0><<<dim3(32, 8, 2), 256, 0, stream>>>(
        ai, w_down, HID, 512, down, nullptr, down_b, nullptr, nullptr, nullptr,
        pn, WgT, g, bg);
    // 10. scores -> softmax over T -> probs, wdown
    scores2<<<TOK, 256, 0, stream>>>(pn, U9, cts, down, g, probs, wdown);
    // 11. mixed = wdown @ w_upmix^T + h + probs@up_b
    gemmA<1><<<dim3(32, 16), 256, 0, stream>>>(
        wdown, w_upmix, 512, HID, mixed, nullptr, nullptr, h_f32, probs, up_b,
        nullptr, nullptr, nullptr, nullptr);
    // 12. fuse = mixed @ value_w^T + it
    gemmA<2><<<dim3(32, 16), 256, 0, stream>>>(
        mixed, w_value, HID, HID, nullptr, fuse, nullptr, it, nullptr, nullptr,
        nullptr, nullptr, nullptr, nullptr);
    // 13. out = LN(fuse)
    ln_out<<<TOK, 256, 0, stream>>>(fuse, ln_g, ln_b, outp);
}